// Round 1
// baseline (2730.525 us; speedup 1.0000x reference)
//
#include <hip/hip_runtime.h>

#define N_NODES 100000
#define N_EDGES 3200000

// -------- Edge kernel: emb = lin1(edge_attr); msg = relu(x[src]+emb);
//          atomically accumulate msg into aggr[dst]. One thread per edge. ----
__global__ __launch_bounds__(256) void gine_edge_kernel(
    const float* __restrict__ x,          // [N,16]
    const int*   __restrict__ ei,         // [2,E]
    const float* __restrict__ ea,         // [E,8]
    const float* __restrict__ w1,         // [16,8]
    const float* __restrict__ b1,         // [16]
    float*       __restrict__ aggr)       // [N,16]
{
    __shared__ float s_w[128];
    __shared__ float s_b[16];
    const int t = threadIdx.x;
    if (t < 128) s_w[t] = w1[t];
    if (t < 16)  s_b[t] = b1[t];
    __syncthreads();

    const int e = blockIdx.x * 256 + t;
    if (e >= N_EDGES) return;

    const int src = ei[e];
    const int dst = ei[N_EDGES + e];

    // edge_attr: 8 contiguous floats -> 2x float4 (coalesced, 32B/thread)
    const float4* eap = reinterpret_cast<const float4*>(ea + (size_t)e * 8);
    const float4 a0 = eap[0];
    const float4 a1 = eap[1];
    const float av[8] = {a0.x, a0.y, a0.z, a0.w, a1.x, a1.y, a1.z, a1.w};

    // gather x[src]: 16 floats (L2/L3-resident, x is only 6.4 MB)
    const float4* xp = reinterpret_cast<const float4*>(x + (size_t)src * 16);
    const float4 x0 = xp[0], x1 = xp[1], x2 = xp[2], x3 = xp[3];
    const float xv[16] = {x0.x, x0.y, x0.z, x0.w,
                          x1.x, x1.y, x1.z, x1.w,
                          x2.x, x2.y, x2.z, x2.w,
                          x3.x, x3.y, x3.z, x3.w};

    float* ag = aggr + (size_t)dst * 16;
    #pragma unroll
    for (int j = 0; j < 16; ++j) {
        float v = s_b[j];
        #pragma unroll
        for (int k = 0; k < 8; ++k)
            v = fmaf(av[k], s_w[j * 8 + k], v);
        v += xv[j];
        v = fmaxf(v, 0.0f);
        // native global_atomic_add_f32 (device-scope); plain atomicAdd(float*)
        // may lower to a CAS loop without -munsafe-fp-atomics.
        unsafeAtomicAdd(ag + j, v);
    }
}

// -------- Node kernel: out = (x + aggr) @ nn_w^T + nn_b. One thread/node. ---
__global__ __launch_bounds__(256) void gine_node_kernel(
    const float* __restrict__ x,          // [N,16]
    const float* __restrict__ aggr,       // [N,16]
    const float* __restrict__ w2,         // [32,16]
    const float* __restrict__ b2,         // [32]
    float*       __restrict__ out)        // [N,32]
{
    __shared__ float s_w[512];
    __shared__ float s_b[32];
    const int t = threadIdx.x;
    s_w[t]       = w2[t];
    s_w[t + 256] = w2[t + 256];
    if (t < 32) s_b[t] = b2[t];
    __syncthreads();

    const int n = blockIdx.x * 256 + t;
    if (n >= N_NODES) return;

    const float4* xp = reinterpret_cast<const float4*>(x    + (size_t)n * 16);
    const float4* ap = reinterpret_cast<const float4*>(aggr + (size_t)n * 16);
    float h[16];
    #pragma unroll
    for (int i = 0; i < 4; ++i) {
        const float4 xv = xp[i];
        const float4 av = ap[i];
        h[4*i + 0] = xv.x + av.x;
        h[4*i + 1] = xv.y + av.y;
        h[4*i + 2] = xv.z + av.z;
        h[4*i + 3] = xv.w + av.w;
    }

    float4* op = reinterpret_cast<float4*>(out + (size_t)n * 32);
    #pragma unroll
    for (int jq = 0; jq < 8; ++jq) {
        float4 o;
        float* po = &o.x;
        #pragma unroll
        for (int jj = 0; jj < 4; ++jj) {
            const int j = jq * 4 + jj;
            float v = s_b[j];
            #pragma unroll
            for (int k = 0; k < 16; ++k)
                v = fmaf(h[k], s_w[j * 16 + k], v);
            po[jj] = v;
        }
        op[jq] = o;
    }
}

extern "C" void kernel_launch(void* const* d_in, const int* in_sizes, int n_in,
                              void* d_out, int out_size, void* d_ws, size_t ws_size,
                              hipStream_t stream) {
    const float* x   = (const float*)d_in[0];
    const int*   ei  = (const int*)  d_in[1];
    const float* ea  = (const float*)d_in[2];
    const float* w1  = (const float*)d_in[3];
    const float* b1  = (const float*)d_in[4];
    const float* w2  = (const float*)d_in[5];
    const float* b2  = (const float*)d_in[6];
    float* out  = (float*)d_out;
    float* aggr = (float*)d_ws;   // [N,16] fp32 = 6.4 MB

    // d_ws is poisoned 0xAA before every timed call — zero the accumulator.
    hipMemsetAsync(aggr, 0, (size_t)N_NODES * 16 * sizeof(float), stream);

    gine_edge_kernel<<<(N_EDGES + 255) / 256, 256, 0, stream>>>(
        x, ei, ea, w1, b1, aggr);

    gine_node_kernel<<<(N_NODES + 255) / 256, 256, 0, stream>>>(
        x, aggr, w2, b2, out);
}

// Round 2
// 1375.056 us; speedup vs baseline: 1.9858x; 1.9858x over previous
//
#include <hip/hip_runtime.h>

#define N_NODES 100000
#define N_EDGES 3200000
#define RCHUNK  1024              // nodes per chunk (LDS accumulator rows)
#define NCHUNK  98                // ceil(N_NODES / RCHUNK)
#define BLK_E   1024
#define QCAP    5120              // worst case: (BLK_E-1) pending + 4*BLK_E pushed
#define BLK_N   512

// -------- Edge kernel: each block owns node chunk [cid*1024, cid*1024+1024)
// and scans edge-slice sid. Matching edges go through an LDS compaction queue
// (keeps the MLP body dense), accumulate via LDS float atomics (channel-major
// layout -> bank = dst&31, conflict-light), then flush the tile to partial[sid].
__global__ __launch_bounds__(BLK_E) void gine_edge_chunk(
    const float* __restrict__ x,          // [N,16]
    const int*   __restrict__ ei,         // [2,E] (src | dst)
    const float* __restrict__ ea,         // [E,8]
    const float* __restrict__ w1,         // [16,8]
    const float* __restrict__ b1,         // [16]
    float*       __restrict__ partial,    // [S][NCHUNK][16][RCHUNK]
    int S)
{
    __shared__ float acc[16 * RCHUNK];    // 64 KB, channel-major [j][node]
    __shared__ int2  queue[QCAP];         // 40 KB: (edge_id, src | dst_local<<17)
    __shared__ float s_w[128];
    __shared__ float s_b[16];
    __shared__ int   s_cnt;

    const int t   = threadIdx.x;
    const int cid = blockIdx.x % NCHUNK;
    const int sid = blockIdx.x / NCHUNK;

    for (int i = t; i < 16 * RCHUNK; i += BLK_E) acc[i] = 0.0f;
    if (t < 128) s_w[t] = w1[t];
    if (t < 16)  s_b[t] = b1[t];
    if (t == 0)  s_cnt = 0;
    __syncthreads();

    const int base = cid * RCHUNK;
    const int4* dst4 = reinterpret_cast<const int4*>(ei + N_EDGES);
    const int qn    = N_EDGES / S / 4;    // int4 elements per slice (S in {1,2,4,8})
    const int qbase = qn * sid;
    const int nIter = (qn + BLK_E - 1) / BLK_E;

    for (int it = 0; it < nIter; ++it) {
        const int qi = it * BLK_E + t;
        int4 d = make_int4(-1, -1, -1, -1);
        if (qi < qn) d = dst4[qbase + qi];           // dense, L3-resident re-read
        const int ebase = (qbase + qi) * 4;
        #pragma unroll
        for (int k = 0; k < 4; ++k) {
            const int dv = (k == 0) ? d.x : (k == 1) ? d.y : (k == 2) ? d.z : d.w;
            const int dl = dv - base;
            if (dl >= 0 && dl < RCHUNK) {
                const int e   = ebase + k;
                const int src = ei[e];               // sparse scattered 4B read
                const int slot = atomicAdd(&s_cnt, 1);
                queue[slot] = make_int2(e, src | (dl << 17));
            }
        }
        __syncthreads();
        const int Q = s_cnt;
        const bool last = (it == nIter - 1);
        if (Q >= BLK_E || (last && Q > 0)) {         // dense drain
            for (int i = t; i < Q; i += BLK_E) {
                const int2 qe = queue[i];
                const int e   = qe.x;
                const int src = qe.y & 0x1FFFF;
                const int dl  = qe.y >> 17;
                const float4* eap = reinterpret_cast<const float4*>(ea) + (size_t)e * 2;
                const float4 a0 = eap[0];
                const float4 a1 = eap[1];
                const float av[8] = {a0.x,a0.y,a0.z,a0.w, a1.x,a1.y,a1.z,a1.w};
                const float4* xp = reinterpret_cast<const float4*>(x) + (size_t)src * 4;
                const float4 x0 = xp[0], x1 = xp[1], x2 = xp[2], x3 = xp[3];
                const float xv[16] = {x0.x,x0.y,x0.z,x0.w, x1.x,x1.y,x1.z,x1.w,
                                      x2.x,x2.y,x2.z,x2.w, x3.x,x3.y,x3.z,x3.w};
                #pragma unroll
                for (int j = 0; j < 16; ++j) {
                    float v = s_b[j];
                    #pragma unroll
                    for (int k = 0; k < 8; ++k)
                        v = fmaf(av[k], s_w[j * 8 + k], v);
                    v += xv[j];
                    v = fmaxf(v, 0.0f);
                    atomicAdd(&acc[j * RCHUNK + dl], v);   // ds_add_f32
                }
            }
            __syncthreads();
            if (t == 0) s_cnt = 0;
        }
        __syncthreads();
    }

    // flush tile -> partial[sid][cid] (fully written every call; ws is poisoned)
    float4* pp = reinterpret_cast<float4*>(partial) +
                 (size_t)(sid * NCHUNK + cid) * (16 * RCHUNK / 4);
    const float4* a4 = reinterpret_cast<const float4*>(acc);
    #pragma unroll
    for (int i = 0; i < 4; ++i)
        pp[t + i * BLK_E] = a4[t + i * BLK_E];
}

// -------- Node kernel: reduce S partials + (x + aggr) @ nn_w^T + nn_b -------
__global__ __launch_bounds__(BLK_N) void gine_node(
    const float* __restrict__ x,          // [N,16]
    const float* __restrict__ partial,    // [S][NCHUNK][16][RCHUNK]
    const float* __restrict__ w2,         // [32,16]
    const float* __restrict__ b2,         // [32]
    float*       __restrict__ out,        // [N,32]
    int S)
{
    __shared__ float s_w[512];
    __shared__ float s_b[32];
    const int t = threadIdx.x;
    s_w[t] = w2[t];
    if (t < 32) s_b[t] = b2[t];
    __syncthreads();

    const int n = blockIdx.x * BLK_N + t;
    if (n >= N_NODES) return;
    const int c = n >> 10;
    const int l = n & (RCHUNK - 1);

    float h[16];
    const float4* xp = reinterpret_cast<const float4*>(x) + (size_t)n * 4;
    #pragma unroll
    for (int i = 0; i < 4; ++i) {
        const float4 xv = xp[i];
        h[4*i + 0] = xv.x; h[4*i + 1] = xv.y; h[4*i + 2] = xv.z; h[4*i + 3] = xv.w;
    }
    for (int s = 0; s < S; ++s) {
        const float* pb = partial + (size_t)(s * NCHUNK + c) * (16 * RCHUNK);
        #pragma unroll
        for (int j = 0; j < 16; ++j)
            h[j] += pb[j * RCHUNK + l];               // lanes -> consecutive l, coalesced
    }

    float4* op = reinterpret_cast<float4*>(out) + (size_t)n * 8;
    #pragma unroll
    for (int jq = 0; jq < 8; ++jq) {
        float4 o;
        float* po = &o.x;
        #pragma unroll
        for (int jj = 0; jj < 4; ++jj) {
            const int j = jq * 4 + jj;
            float v = s_b[j];
            #pragma unroll
            for (int k = 0; k < 16; ++k)
                v = fmaf(h[k], s_w[j * 16 + k], v);
            po[jj] = v;
        }
        op[jq] = o;
    }
}

extern "C" void kernel_launch(void* const* d_in, const int* in_sizes, int n_in,
                              void* d_out, int out_size, void* d_ws, size_t ws_size,
                              hipStream_t stream) {
    const float* x  = (const float*)d_in[0];
    const int*   ei = (const int*)  d_in[1];
    const float* ea = (const float*)d_in[2];
    const float* w1 = (const float*)d_in[3];
    const float* b1 = (const float*)d_in[4];
    const float* w2 = (const float*)d_in[5];
    const float* b2 = (const float*)d_in[6];
    float* out = (float*)d_out;

    // Partial buffers: S copies of [NCHUNK][16][RCHUNK] f32 (6.42 MB each).
    // S must be a power of two (edge slicing divides E evenly) and fit ws.
    int S = 8;
    const size_t perSlice = (size_t)NCHUNK * 16 * RCHUNK * sizeof(float);
    while (S > 1 && perSlice * (size_t)S > ws_size) S >>= 1;

    gine_edge_chunk<<<NCHUNK * S, BLK_E, 0, stream>>>(
        x, ei, ea, w1, b1, (float*)d_ws, S);

    gine_node<<<(N_NODES + BLK_N - 1) / BLK_N, BLK_N, 0, stream>>>(
        x, (const float*)d_ws, w2, b2, out, S);
}

// Round 3
// 827.617 us; speedup vs baseline: 3.2993x; 1.6615x over previous
//
#include <hip/hip_runtime.h>

#define N_NODES 100000
#define N_EDGES 3200000
#define RCHUNK  2048              // nodes per chunk
#define NCHUNK  49                // ceil(100000/2048)
#define NSEG    (N_EDGES / 16)    // 200000 16-edge segments
#define BLK_E   1024
#define WQ_CAP  320               // 63 pending + 256 pushed (4 k-slots) max
#define BLK_N   512
#define SMAX    10

// ---- Pack kernel: cid8[e] = dst>>11 (1B); pk[e] = src | (dst&2047)<<17 ----
__global__ __launch_bounds__(256) void gine_pack(
    const int* __restrict__ ei, unsigned char* __restrict__ cid8,
    int* __restrict__ pk)
{
    const int i = blockIdx.x * 256 + threadIdx.x;      // int4 index
    if (i >= N_EDGES / 4) return;
    const int4 s4 = reinterpret_cast<const int4*>(ei)[i];
    const int4 d4 = reinterpret_cast<const int4*>(ei + N_EDGES)[i];
    const unsigned cw = (unsigned)(d4.x >> 11)
                      | ((unsigned)(d4.y >> 11) << 8)
                      | ((unsigned)(d4.z >> 11) << 16)
                      | ((unsigned)(d4.w >> 11) << 24);
    reinterpret_cast<unsigned*>(cid8)[i] = cw;
    int4 p;
    p.x = s4.x | ((d4.x & (RCHUNK - 1)) << 17);
    p.y = s4.y | ((d4.y & (RCHUNK - 1)) << 17);
    p.z = s4.z | ((d4.z & (RCHUNK - 1)) << 17);
    p.w = s4.w | ((d4.w & (RCHUNK - 1)) << 17);
    reinterpret_cast<int4*>(pk)[i] = p;
}

// ---- Edge kernel: block (cid,sid) scans 1B cids of its edge slice;
//      per-wave ballot-compacted queues; dense 64-wide MLP drains;
//      LDS fp32 accumulate; flush tile to partial[sid][cid]. No barriers
//      in the hot loop, no shared counters. ----
__global__ __launch_bounds__(BLK_E, 4) void gine_edge(
    const float* __restrict__ x,          // [N,16]
    const float* __restrict__ ea,         // [E,8]
    const unsigned char* __restrict__ cid8,
    const int*   __restrict__ pk,
    const float* __restrict__ w1,         // [16,8]
    const float* __restrict__ b1,         // [16]
    float*       __restrict__ partial,    // [S][NCHUNK][16][RCHUNK]
    int S)
{
    __shared__ float acc[16 * RCHUNK];    // 128 KB, channel-major [j][node]
    __shared__ int   wq[16][WQ_CAP];      // 20 KB per-wave queues
    __shared__ float s_w[128];
    __shared__ float s_b[16];

    const int t    = threadIdx.x;
    const int lane = t & 63;
    const int wid  = t >> 6;
    const int cid  = blockIdx.x % NCHUNK;
    const int sid  = blockIdx.x / NCHUNK;

    for (int i = t; i < 16 * RCHUNK / 4; i += BLK_E)
        reinterpret_cast<float4*>(acc)[i] = make_float4(0.f, 0.f, 0.f, 0.f);
    if (t < 128) s_w[t] = w1[t];
    if (t < 16)  s_b[t] = b1[t];
    __syncthreads();

    auto body = [&](int e) {
        const int pe  = pk[e];
        const int src = pe & 0x1FFFF;
        const int dl  = pe >> 17;
        const float4* eap = reinterpret_cast<const float4*>(ea) + (size_t)e * 2;
        const float4 a0 = eap[0];
        const float4 a1 = eap[1];
        const float av[8] = {a0.x,a0.y,a0.z,a0.w, a1.x,a1.y,a1.z,a1.w};
        const float4* xp = reinterpret_cast<const float4*>(x) + (size_t)src * 4;
        const float4 x0 = xp[0], x1 = xp[1], x2 = xp[2], x3 = xp[3];
        const float xv[16] = {x0.x,x0.y,x0.z,x0.w, x1.x,x1.y,x1.z,x1.w,
                              x2.x,x2.y,x2.z,x2.w, x3.x,x3.y,x3.z,x3.w};
        #pragma unroll
        for (int j = 0; j < 16; ++j) {
            float v = s_b[j];
            #pragma unroll
            for (int k = 0; k < 8; ++k)
                v = fmaf(av[k], s_w[j * 8 + k], v);
            v = fmaxf(v + xv[j], 0.0f);
            __hip_atomic_fetch_add(&acc[j * RCHUNK + dl], v,
                                   __ATOMIC_RELAXED, __HIP_MEMORY_SCOPE_WORKGROUP);
        }
    };

    const long long s0 = (long long)NSEG * sid / S;
    const long long s1 = (long long)NSEG * (sid + 1) / S;
    const unsigned long long ltmask = (1ull << lane) - 1ull;
    int cnt = 0;                           // wave-uniform queue count

    for (long long sb = s0; sb < s1; sb += BLK_E) {
        const long long seg = sb + t;
        uint4 cw = make_uint4(~0u, ~0u, ~0u, ~0u);   // 255 != cid -> no match
        if (seg < s1) cw = reinterpret_cast<const uint4*>(cid8)[seg];
        const int ebase = (int)(seg << 4);
        const unsigned w4[4] = {cw.x, cw.y, cw.z, cw.w};
        #pragma unroll
        for (int g = 0; g < 4; ++g) {      // 4 k-slots per drain-check
            #pragma unroll
            for (int kk = 0; kk < 4; ++kk) {
                const int k = g * 4 + kk;
                const unsigned c = (w4[g] >> (8 * kk)) & 255u;
                const bool m = (c == (unsigned)cid);
                const unsigned long long mask = __ballot(m);
                if (m) wq[wid][cnt + __popcll(mask & ltmask)] = ebase + k;
                cnt += __popcll(mask);
            }
            while (cnt >= 64) {            // dense drain, 100% lanes active
                body(wq[wid][cnt - 64 + lane]);
                cnt -= 64;
            }
        }
    }
    while (cnt > 0) {                      // tail drain (masked)
        const int take = cnt < 64 ? cnt : 64;
        if (lane < take) body(wq[wid][cnt - take + lane]);
        cnt -= take;
    }

    __syncthreads();
    float4* pp = reinterpret_cast<float4*>(partial) +
                 (size_t)(sid * NCHUNK + cid) * (16 * RCHUNK / 4);
    const float4* a4 = reinterpret_cast<const float4*>(acc);
    for (int i = t; i < 16 * RCHUNK / 4; i += BLK_E)
        pp[i] = a4[i];
}

// ---- Node kernel: reduce S partials + (x + aggr) @ nn_w^T + nn_b ----
__global__ __launch_bounds__(BLK_N) void gine_node(
    const float* __restrict__ x,          // [N,16]
    const float* __restrict__ partial,    // [S][NCHUNK][16][RCHUNK]
    const float* __restrict__ w2,         // [32,16]
    const float* __restrict__ b2,         // [32]
    float*       __restrict__ out,        // [N,32]
    int S)
{
    __shared__ float s_w[512];
    __shared__ float s_b[32];
    const int t = threadIdx.x;
    s_w[t] = w2[t];
    if (t < 32) s_b[t] = b2[t];
    __syncthreads();

    const int n = blockIdx.x * BLK_N + t;
    if (n >= N_NODES) return;
    const int c = n >> 11;
    const int l = n & (RCHUNK - 1);

    float h[16];
    const float4* xp = reinterpret_cast<const float4*>(x) + (size_t)n * 4;
    #pragma unroll
    for (int i = 0; i < 4; ++i) {
        const float4 xv = xp[i];
        h[4*i+0] = xv.x; h[4*i+1] = xv.y; h[4*i+2] = xv.z; h[4*i+3] = xv.w;
    }
    for (int s = 0; s < S; ++s) {
        const float* pb = partial + (size_t)(s * NCHUNK + c) * (16 * RCHUNK);
        #pragma unroll
        for (int j = 0; j < 16; ++j)
            h[j] += pb[j * RCHUNK + l];    // lanes -> consecutive l, coalesced
    }

    float4* op = reinterpret_cast<float4*>(out) + (size_t)n * 8;
    #pragma unroll
    for (int jq = 0; jq < 8; ++jq) {
        float4 o;
        float* po = &o.x;
        #pragma unroll
        for (int jj = 0; jj < 4; ++jj) {
            const int j = jq * 4 + jj;
            float v = s_b[j];
            #pragma unroll
            for (int k = 0; k < 16; ++k)
                v = fmaf(h[k], s_w[j * 16 + k], v);
            po[jj] = v;
        }
        op[jq] = o;
    }
}

extern "C" void kernel_launch(void* const* d_in, const int* in_sizes, int n_in,
                              void* d_out, int out_size, void* d_ws, size_t ws_size,
                              hipStream_t stream) {
    const float* x  = (const float*)d_in[0];
    const int*   ei = (const int*)  d_in[1];
    const float* ea = (const float*)d_in[2];
    const float* w1 = (const float*)d_in[3];
    const float* b1 = (const float*)d_in[4];
    const float* w2 = (const float*)d_in[5];
    const float* b2 = (const float*)d_in[6];
    float* out = (float*)d_out;

    // ws layout: [cid8 3.2MB][pk 12.8MB][partials S x 6.42MB]
    unsigned char* cid8 = (unsigned char*)d_ws;
    int*   pk      = (int*)((char*)d_ws + 3200000);
    float* partial = (float*)((char*)d_ws + 16000000);
    const long long perSlice = (long long)NCHUNK * 16 * RCHUNK * 4;  // 6422528
    long long avail = (long long)ws_size - 16000000LL;
    int S = (int)(avail / perSlice);
    if (S > SMAX) S = SMAX;
    if (S < 1) S = 1;

    gine_pack<<<N_EDGES / 4 / 256, 256, 0, stream>>>(ei, cid8, pk);
    gine_edge<<<NCHUNK * S, BLK_E, 0, stream>>>(x, ea, cid8, pk, w1, b1, partial, S);
    gine_node<<<(N_NODES + BLK_N - 1) / BLK_N, BLK_N, 0, stream>>>(
        x, partial, w2, b2, out, S);
}

// Round 5
// 724.989 us; speedup vs baseline: 3.7663x; 1.1416x over previous
//
#include <hip/hip_runtime.h>

#define N_NODES 100000
#define N_EDGES 3200000
#define RCHUNK  1024              // nodes per chunk
#define NCHUNK  98                // ceil(100000/1024)
#define NSEG    (N_EDGES / 16)    // 200000 16-edge segments
#define BLK_E   512
#define NWAVE   (BLK_E / 64)
#define WQ_CAP  384               // 255 pending + 128 pushed (2 byte-slots) max
#define BLK_N   512
#define SMAX    5

// ---- Pack kernel: cid8[e] = dst>>10 (1B); pk[e] = src | (dst&1023)<<17 ----
__global__ __launch_bounds__(256) void gine_pack(
    const int* __restrict__ ei, unsigned char* __restrict__ cid8,
    int* __restrict__ pk)
{
    const int i = blockIdx.x * 256 + threadIdx.x;      // int4 index
    if (i >= N_EDGES / 4) return;
    const int4 s4 = reinterpret_cast<const int4*>(ei)[i];
    const int4 d4 = reinterpret_cast<const int4*>(ei + N_EDGES)[i];
    const unsigned cw = (unsigned)(d4.x >> 10)
                      | ((unsigned)(d4.y >> 10) << 8)
                      | ((unsigned)(d4.z >> 10) << 16)
                      | ((unsigned)(d4.w >> 10) << 24);
    reinterpret_cast<unsigned*>(cid8)[i] = cw;
    int4 p;
    p.x = s4.x | ((d4.x & (RCHUNK - 1)) << 17);
    p.y = s4.y | ((d4.y & (RCHUNK - 1)) << 17);
    p.z = s4.z | ((d4.z & (RCHUNK - 1)) << 17);
    p.w = s4.w | ((d4.w & (RCHUNK - 1)) << 17);
    reinterpret_cast<int4*>(pk)[i] = p;
}

// ---- Edge kernel: per-wave ballot queues + ILP-4 dense drains ----
__global__ __launch_bounds__(BLK_E, 4) void gine_edge(
    const float* __restrict__ x,          // [N,16]
    const float* __restrict__ ea,         // [E,8]
    const unsigned char* __restrict__ cid8,
    const int*   __restrict__ pk,
    const float* __restrict__ w1,         // [16,8]
    const float* __restrict__ b1,         // [16]
    float*       __restrict__ partial,    // [S][NCHUNK][16][RCHUNK]
    int S)
{
    __shared__ float acc[16 * RCHUNK];    // 64 KB, channel-major [j][node]
    __shared__ int   wq[NWAVE][WQ_CAP];   // 12 KB per-wave queues
    __shared__ float s_w[128];
    __shared__ float s_b[16];

    const int t    = threadIdx.x;
    const int lane = t & 63;
    const int wid  = t >> 6;
    const int cid  = blockIdx.x % NCHUNK;
    const int sid  = blockIdx.x / NCHUNK;

    for (int i = t; i < 16 * RCHUNK / 4; i += BLK_E)
        reinterpret_cast<float4*>(acc)[i] = make_float4(0.f, 0.f, 0.f, 0.f);
    if (t < 128) s_w[t] = w1[t];
    if (t < 16)  s_b[t] = b1[t];
    __syncthreads();

    // single-edge body (tail drains)
    auto body = [&](int e) {
        const int pe  = pk[e];
        const int src = pe & 0x1FFFF;
        const int dl  = pe >> 17;
        const float4* eap = reinterpret_cast<const float4*>(ea) + (size_t)e * 2;
        const float4 a0 = eap[0];
        const float4 a1 = eap[1];
        const float av[8] = {a0.x,a0.y,a0.z,a0.w, a1.x,a1.y,a1.z,a1.w};
        const float4* xp = reinterpret_cast<const float4*>(x) + (size_t)src * 4;
        const float4 x0 = xp[0], x1 = xp[1], x2 = xp[2], x3 = xp[3];
        const float xv[16] = {x0.x,x0.y,x0.z,x0.w, x1.x,x1.y,x1.z,x1.w,
                              x2.x,x2.y,x2.z,x2.w, x3.x,x3.y,x3.z,x3.w};
        #pragma unroll
        for (int j = 0; j < 16; ++j) {
            float v = s_b[j];
            #pragma unroll
            for (int k = 0; k < 8; ++k)
                v = fmaf(av[k], s_w[j * 8 + k], v);
            v = fmaxf(v + xv[j], 0.0f);
            __hip_atomic_fetch_add(&acc[j * RCHUNK + dl], v,
                                   __ATOMIC_RELAXED, __HIP_MEMORY_SCOPE_WORKGROUP);
        }
    };

    // ILP-4 drain: 256 edges per wave, 4 per lane, all loads front-issued
    auto drain4 = [&](int qb) {
        int e[4], p[4];
        #pragma unroll
        for (int i = 0; i < 4; ++i) e[i] = wq[wid][qb + i * 64 + lane];
        #pragma unroll
        for (int i = 0; i < 4; ++i) p[i] = pk[e[i]];
        float4 a0[4], a1[4];
        #pragma unroll
        for (int i = 0; i < 4; ++i) {
            const float4* eap = reinterpret_cast<const float4*>(ea) + (size_t)e[i] * 2;
            a0[i] = eap[0]; a1[i] = eap[1];
        }
        float4 xr[4][4];
        #pragma unroll
        for (int i = 0; i < 4; ++i) {
            const float4* xp = reinterpret_cast<const float4*>(x)
                             + (size_t)(p[i] & 0x1FFFF) * 4;
            #pragma unroll
            for (int q = 0; q < 4; ++q) xr[i][q] = xp[q];
        }
        #pragma unroll
        for (int i = 0; i < 4; ++i) {
            const int dl = p[i] >> 17;
            const float av[8] = {a0[i].x,a0[i].y,a0[i].z,a0[i].w,
                                 a1[i].x,a1[i].y,a1[i].z,a1[i].w};
            float v[16];
            #pragma unroll
            for (int j = 0; j < 16; ++j) {
                float s = s_b[j];
                #pragma unroll
                for (int k = 0; k < 8; ++k)
                    s = fmaf(av[k], s_w[j * 8 + k], s);
                v[j] = s;
            }
            const float xv[16] = {xr[i][0].x,xr[i][0].y,xr[i][0].z,xr[i][0].w,
                                  xr[i][1].x,xr[i][1].y,xr[i][1].z,xr[i][1].w,
                                  xr[i][2].x,xr[i][2].y,xr[i][2].z,xr[i][2].w,
                                  xr[i][3].x,xr[i][3].y,xr[i][3].z,xr[i][3].w};
            #pragma unroll
            for (int j = 0; j < 16; ++j) {
                const float r = fmaxf(v[j] + xv[j], 0.0f);
                __hip_atomic_fetch_add(&acc[j * RCHUNK + dl], r,
                                       __ATOMIC_RELAXED, __HIP_MEMORY_SCOPE_WORKGROUP);
            }
        }
    };

    const long long s0 = (long long)NSEG * sid / S;
    const long long s1 = (long long)NSEG * (sid + 1) / S;
    const unsigned long long ltmask = (1ull << lane) - 1ull;
    int cnt = 0;                           // wave-uniform queue count

    for (long long sb = s0; sb < s1; sb += BLK_E) {
        const long long seg = sb + t;
        uint4 cw = make_uint4(~0u, ~0u, ~0u, ~0u);   // 255 matches no cid
        if (seg < s1) cw = reinterpret_cast<const uint4*>(cid8)[seg];
        const int ebase = (int)(seg << 4);
        const unsigned w4[4] = {cw.x, cw.y, cw.z, cw.w};
        #pragma unroll
        for (int w = 0; w < 4; ++w) {
            #pragma unroll
            for (int h = 0; h < 2; ++h) {  // drain-check every 2 byte-slots
                #pragma unroll
                for (int kk = 0; kk < 2; ++kk) {
                    const int b = h * 2 + kk;
                    const unsigned c = (w4[w] >> (8 * b)) & 255u;
                    const bool m = (c == (unsigned)cid);
                    const unsigned long long mask = __ballot(m);
                    if (m) wq[wid][cnt + __popcll(mask & ltmask)] = ebase + w * 4 + b;
                    cnt += __popcll(mask);
                }
                while (cnt >= 256) { drain4(cnt - 256); cnt -= 256; }
            }
        }
    }
    // tail drains
    while (cnt >= 64) {
        #pragma unroll 1
        for (int z = 0; z < 1; ++z) body(wq[wid][cnt - 64 + lane]);
        cnt -= 64;
    }
    if (cnt > 0) {
        if (lane < cnt) body(wq[wid][lane]);
    }

    __syncthreads();
    float4* pp = reinterpret_cast<float4*>(partial) +
                 (size_t)(sid * NCHUNK + cid) * (16 * RCHUNK / 4);
    const float4* a4 = reinterpret_cast<const float4*>(acc);
    for (int i = t; i < 16 * RCHUNK / 4; i += BLK_E)
        pp[i] = a4[i];
}

// ---- Node kernel: reduce S partials + (x + aggr) @ nn_w^T + nn_b ----
__global__ __launch_bounds__(BLK_N) void gine_node(
    const float* __restrict__ x,          // [N,16]
    const float* __restrict__ partial,    // [S][NCHUNK][16][RCHUNK]
    const float* __restrict__ w2,         // [32,16]
    const float* __restrict__ b2,         // [32]
    float*       __restrict__ out,        // [N,32]
    int S)
{
    __shared__ float s_w[512];
    __shared__ float s_b[32];
    const int t = threadIdx.x;
    s_w[t] = w2[t];
    if (t < 32) s_b[t] = b2[t];
    __syncthreads();

    const int n = blockIdx.x * BLK_N + t;
    if (n >= N_NODES) return;
    const int c = n >> 10;
    const int l = n & (RCHUNK - 1);

    float h[16];
    const float4* xp = reinterpret_cast<const float4*>(x) + (size_t)n * 4;
    #pragma unroll
    for (int i = 0; i < 4; ++i) {
        const float4 xv = xp[i];
        h[4*i+0] = xv.x; h[4*i+1] = xv.y; h[4*i+2] = xv.z; h[4*i+3] = xv.w;
    }
    for (int s = 0; s < S; ++s) {
        const float* pb = partial + (size_t)(s * NCHUNK + c) * (16 * RCHUNK);
        #pragma unroll
        for (int j = 0; j < 16; ++j)
            h[j] += pb[j * RCHUNK + l];    // lanes -> consecutive l, coalesced
    }

    float4* op = reinterpret_cast<float4*>(out) + (size_t)n * 8;
    #pragma unroll
    for (int jq = 0; jq < 8; ++jq) {
        float4 o;
        float* po = &o.x;
        #pragma unroll
        for (int jj = 0; jj < 4; ++jj) {
            const int j = jq * 4 + jj;
            float v = s_b[j];
            #pragma unroll
            for (int k = 0; k < 16; ++k)
                v = fmaf(h[k], s_w[j * 16 + k], v);
            po[jj] = v;
        }
        op[jq] = o;
    }
}

extern "C" void kernel_launch(void* const* d_in, const int* in_sizes, int n_in,
                              void* d_out, int out_size, void* d_ws, size_t ws_size,
                              hipStream_t stream) {
    const float* x  = (const float*)d_in[0];
    const int*   ei = (const int*)  d_in[1];
    const float* ea = (const float*)d_in[2];
    const float* w1 = (const float*)d_in[3];
    const float* b1 = (const float*)d_in[4];
    const float* w2 = (const float*)d_in[5];
    const float* b2 = (const float*)d_in[6];
    float* out = (float*)d_out;

    // ws layout: [cid8 3.2MB][pk 12.8MB][partials S x 6.42MB]
    unsigned char* cid8 = (unsigned char*)d_ws;
    int*   pk      = (int*)((char*)d_ws + 3200000);
    float* partial = (float*)((char*)d_ws + 16000000);
    const long long perSlice = (long long)NCHUNK * 16 * RCHUNK * 4;  // 6422528
    int S = SMAX;
    while (S > 1 && 16000000LL + (long long)S * perSlice > (long long)ws_size) --S;

    gine_pack<<<N_EDGES / 4 / 256, 256, 0, stream>>>(ei, cid8, pk);
    gine_edge<<<NCHUNK * S, BLK_E, 0, stream>>>(x, ea, cid8, pk, w1, b1, partial, S);
    gine_node<<<(N_NODES + BLK_N - 1) / BLK_N, BLK_N, 0, stream>>>(
        x, partial, w2, b2, out, S);
}